// Round 6
// baseline (52.851 us; speedup 1.0000x reference)
//
#include <hip/hip_runtime.h>

#define IMG    512
#define BAND   2            // output rows per wave
#define NBANDS 4096         // 16 images x 256 bands
#define NPIX   (16.0 * 512.0 * 512.0)
#define EPS    1e-5f
#define INV81  (1.0f / 81.0f)

struct Rows { float4 i0, i1, j0, j1; };

__device__ __forceinline__ Rows load_rows(const float* __restrict__ Ib,
                                          const float* __restrict__ Jb,
                                          int y, int col0)
{
    Rows r;
    if (y >= 0 && y < IMG) {          // wave-uniform (y uniform per wave)
        const float* rI = Ib + (size_t)y * IMG + col0;
        const float* rJ = Jb + (size_t)y * IMG + col0;
        r.i0 = *(const float4*)(rI);
        r.i1 = *(const float4*)(rI + 4);
        r.j0 = *(const float4*)(rJ);
        r.j1 = *(const float4*)(rJ + 4);
    } else {
        r.i0 = r.i1 = r.j0 = r.j1 = float4{0.f, 0.f, 0.f, 0.f};
    }
    return r;
}

#define ACC(c, xv, yv)                          \
    sI[c]  += (xv); sJ[c] += (yv);              \
    sII[c]  = fmaf((xv), (xv), sII[c]);         \
    sJJ[c]  = fmaf((yv), (yv), sJJ[c]);         \
    sIJ[c]  = fmaf((xv), (yv), sIJ[c]);

#define UPD(c, nx, ny, ox, oy)                                  \
    sI[c]  += (nx) - (ox);                                      \
    sJ[c]  += (ny) - (oy);                                      \
    sII[c]  = fmaf((nx), (nx), fmaf(-(ox), (ox), sII[c]));      \
    sJJ[c]  = fmaf((ny), (ny), fmaf(-(oy), (oy), sJJ[c]));      \
    sIJ[c]  = fmaf((nx), (ny), fmaf(-(ox), (oy), sIJ[c]));

// NOTE: parameter must NOT be named `w` — the body's `.w` member accesses
// would be macro-substituted (that was round 4's compile failure).
#define ACC_ROWS(R)                              \
    ACC(0, R.i0.x, R.j0.x) ACC(1, R.i0.y, R.j0.y)\
    ACC(2, R.i0.z, R.j0.z) ACC(3, R.i0.w, R.j0.w)\
    ACC(4, R.i1.x, R.j1.x) ACC(5, R.i1.y, R.j1.y)\
    ACC(6, R.i1.z, R.j1.z) ACC(7, R.i1.w, R.j1.w)

#define UPD_ROWS(NR, OR)                                                  \
    UPD(0, NR.i0.x, NR.j0.x, OR.i0.x, OR.j0.x)                            \
    UPD(1, NR.i0.y, NR.j0.y, OR.i0.y, OR.j0.y)                            \
    UPD(2, NR.i0.z, NR.j0.z, OR.i0.z, OR.j0.z)                            \
    UPD(3, NR.i0.w, NR.j0.w, OR.i0.w, OR.j0.w)                            \
    UPD(4, NR.i1.x, NR.j1.x, OR.i1.x, OR.j1.x)                            \
    UPD(5, NR.i1.y, NR.j1.y, OR.i1.y, OR.j1.y)                            \
    UPD(6, NR.i1.z, NR.j1.z, OR.i1.z, OR.j1.z)                            \
    UPD(7, NR.i1.w, NR.j1.w, OR.i1.w, OR.j1.w)

// Horizontal 9-window over one quantity's 8 column-sums.
// Halo column-sums come from neighbor lanes; lane 0/63 masked = zero pad.
__device__ __forceinline__ void hwin(const float s[8], int lane, float w[8])
{
    float l[4], r[4];
    #pragma unroll
    for (int i = 0; i < 4; ++i) {
        float lv = __shfl_up(s[4 + i], 1, 64);
        float rv = __shfl_down(s[i],   1, 64);
        l[i] = (lane == 0)  ? 0.f : lv;
        r[i] = (lane == 63) ? 0.f : rv;
    }
    w[0] = ((l[0] + l[1]) + (l[2] + l[3])) +
           ((s[0] + s[1]) + (s[2] + s[3])) + s[4];
    w[1] = w[0] + s[5] - l[0];
    w[2] = w[1] + s[6] - l[1];
    w[3] = w[2] + s[7] - l[2];
    w[4] = w[3] + r[0] - l[3];
    w[5] = w[4] + r[1] - s[0];
    w[6] = w[5] + r[2] - s[1];
    w[7] = w[6] + r[3] - s[2];
}

// One wave = one 2-row band, full 512-col width; lane owns 8 output cols.
// Vertical 9-sums of {I,J,I2,J2,IJ} in 40 regs; one sliding transition
// (old row reused from warm-up's first load). 4096 waves = 4 waves/SIMD
// (VGPR capped at 128 via launch_bounds). Partial -> private ws slot.
__global__ __launch_bounds__(256, 4) void ncc_band_kernel(
    const float* __restrict__ I, const float* __restrict__ J,
    double* __restrict__ slots)
{
    const int lane = threadIdx.x & 63;
    const int wid  = threadIdx.x >> 6;
    const int band = blockIdx.x * 4 + wid;        // 0..4095
    const int img  = band >> 8;                   // 256 bands / image
    const int y0   = (band & 255) * BAND;
    const int col0 = lane * 8;

    const float* Ib = I + (size_t)img * IMG * IMG;
    const float* Jb = J + (size_t)img * IMG * IMG;

    // issue the long-distance loads first: outgoing row (also warm-up's
    // first row) and incoming row (not needed until after first hpass)
    Rows od = load_rows(Ib, Jb, y0 - 4, col0);
    Rows nw = load_rows(Ib, Jb, y0 + 5, col0);

    float sI[8], sJ[8], sII[8], sJJ[8], sIJ[8];
    #pragma unroll
    for (int c = 0; c < 8; ++c) { sI[c]=0.f; sJ[c]=0.f; sII[c]=0.f; sJJ[c]=0.f; sIJ[c]=0.f; }

    ACC_ROWS(od)                                  // row y0-4
    #pragma unroll
    for (int r = -3; r <= 4; ++r) {               // rows y0-3 .. y0+4
        Rows rr = load_rows(Ib, Jb, y0 + r, col0);
        ACC_ROWS(rr)
    }

    float local = 0.0f;

    // per-row: horizontal windows per quantity (shared transient t),
    // folding into cross/Iv/Jv immediately to cap live registers.
    auto hpass = [&]() {
        float wI[8], wJ[8], t[8], cross[8], Iv[8], Jv[8];
        hwin(sI, lane, wI);
        hwin(sJ, lane, wJ);
        hwin(sIJ, lane, t);
        #pragma unroll
        for (int k = 0; k < 8; ++k)
            cross[k] = fmaxf(fmaf(-wI[k] * INV81, wJ[k], t[k]), EPS);
        hwin(sII, lane, t);
        #pragma unroll
        for (int k = 0; k < 8; ++k)
            Iv[k] = fmaxf(fmaf(-wI[k] * INV81, wI[k], t[k]), EPS);
        hwin(sJJ, lane, t);
        #pragma unroll
        for (int k = 0; k < 8; ++k)
            Jv[k] = fmaxf(fmaf(-wJ[k] * INV81, wJ[k], t[k]), EPS);
        #pragma unroll
        for (int k = 0; k < 8; ++k)
            local += (cross[k] * cross[k]) * __builtin_amdgcn_rcpf(Iv[k] * Jv[k]);
    };

    hpass();                 // output row y0
    UPD_ROWS(nw, od)         // slide: +row y0+5, -row y0-4
    hpass();                 // output row y0+1

    // wave reduction + private slot write (no atomic, no init needed)
    #pragma unroll
    for (int off = 32; off > 0; off >>= 1)
        local += __shfl_down(local, off, 64);
    if (lane == 0)
        slots[band] = (double)local;
}

__global__ __launch_bounds__(256) void ncc_finalize_kernel(
    const double* __restrict__ slots, float* __restrict__ out)
{
    const int tid = threadIdx.x;
    double t = 0.0;
    #pragma unroll
    for (int i = 0; i < NBANDS / 256; ++i)
        t += slots[tid + i * 256];
    #pragma unroll
    for (int off = 32; off > 0; off >>= 1)
        t += __shfl_down(t, off, 64);

    __shared__ double wsum[4];
    if ((tid & 63) == 0) wsum[tid >> 6] = t;
    __syncthreads();
    if (tid == 0)
        out[0] = (float)(-(wsum[0] + wsum[1] + wsum[2] + wsum[3]) / NPIX);
}

extern "C" void kernel_launch(void* const* d_in, const int* in_sizes, int n_in,
                              void* d_out, int out_size, void* d_ws, size_t ws_size,
                              hipStream_t stream)
{
    const float* I = (const float*)d_in[0];   // y_true
    const float* J = (const float*)d_in[1];   // y_pred
    float* out = (float*)d_out;
    double* slots = (double*)d_ws;            // 4096 doubles, all written each call

    // 4096 bands (16 images x 256 bands of 2 rows), 4 waves/block -> 1024 blocks
    ncc_band_kernel<<<1024, 256, 0, stream>>>(I, J, slots);
    ncc_finalize_kernel<<<1, 256, 0, stream>>>(slots, out);
}

// Round 7
// 22.627 us; speedup vs baseline: 2.3358x; 2.3358x over previous
//
#include <hip/hip_runtime.h>

#define IMG    512
#define BAND   2            // output rows per wave
#define NBANDS 4096         // 16 images x 256 bands
#define NPIX   (16.0 * 512.0 * 512.0)
#define EPS    1e-5f
#define INV81  (1.0f / 81.0f)

struct Rows { float4 i0, i1, j0, j1; };

__device__ __forceinline__ Rows load_rows(const float* __restrict__ Ib,
                                          const float* __restrict__ Jb,
                                          int y, int col0)
{
    Rows r;
    if (y >= 0 && y < IMG) {          // wave-uniform (y uniform per wave)
        const float* rI = Ib + (size_t)y * IMG + col0;
        const float* rJ = Jb + (size_t)y * IMG + col0;
        r.i0 = *(const float4*)(rI);
        r.i1 = *(const float4*)(rI + 4);
        r.j0 = *(const float4*)(rJ);
        r.j1 = *(const float4*)(rJ + 4);
    } else {
        r.i0 = r.i1 = r.j0 = r.j1 = float4{0.f, 0.f, 0.f, 0.f};
    }
    return r;
}

#define ACC(c, xv, yv)                          \
    sI[c]  += (xv); sJ[c] += (yv);              \
    sII[c]  = fmaf((xv), (xv), sII[c]);         \
    sJJ[c]  = fmaf((yv), (yv), sJJ[c]);         \
    sIJ[c]  = fmaf((xv), (yv), sIJ[c]);

#define UPD(c, nx, ny, ox, oy)                                  \
    sI[c]  += (nx) - (ox);                                      \
    sJ[c]  += (ny) - (oy);                                      \
    sII[c]  = fmaf((nx), (nx), fmaf(-(ox), (ox), sII[c]));      \
    sJJ[c]  = fmaf((ny), (ny), fmaf(-(oy), (oy), sJJ[c]));      \
    sIJ[c]  = fmaf((nx), (ny), fmaf(-(ox), (oy), sIJ[c]));

// NOTE: parameter must NOT be named `w` — the body's `.w` member accesses
// would be macro-substituted (round 4's compile failure).
#define ACC_ROWS(R)                              \
    ACC(0, R.i0.x, R.j0.x) ACC(1, R.i0.y, R.j0.y)\
    ACC(2, R.i0.z, R.j0.z) ACC(3, R.i0.w, R.j0.w)\
    ACC(4, R.i1.x, R.j1.x) ACC(5, R.i1.y, R.j1.y)\
    ACC(6, R.i1.z, R.j1.z) ACC(7, R.i1.w, R.j1.w)

#define UPD_ROWS(NR, OR)                                                  \
    UPD(0, NR.i0.x, NR.j0.x, OR.i0.x, OR.j0.x)                            \
    UPD(1, NR.i0.y, NR.j0.y, OR.i0.y, OR.j0.y)                            \
    UPD(2, NR.i0.z, NR.j0.z, OR.i0.z, OR.j0.z)                            \
    UPD(3, NR.i0.w, NR.j0.w, OR.i0.w, OR.j0.w)                            \
    UPD(4, NR.i1.x, NR.j1.x, OR.i1.x, OR.j1.x)                            \
    UPD(5, NR.i1.y, NR.j1.y, OR.i1.y, OR.j1.y)                            \
    UPD(6, NR.i1.z, NR.j1.z, OR.i1.z, OR.j1.z)                            \
    UPD(7, NR.i1.w, NR.j1.w, OR.i1.w, OR.j1.w)

// Horizontal 9-window over one quantity's 8 column-sums.
// Halo column-sums come from neighbor lanes; lane 0/63 masked = zero pad.
__device__ __forceinline__ void hwin(const float s[8], int lane, float w[8])
{
    float l[4], r[4];
    #pragma unroll
    for (int i = 0; i < 4; ++i) {
        float lv = __shfl_up(s[4 + i], 1, 64);
        float rv = __shfl_down(s[i],   1, 64);
        l[i] = (lane == 0)  ? 0.f : lv;
        r[i] = (lane == 63) ? 0.f : rv;
    }
    w[0] = ((l[0] + l[1]) + (l[2] + l[3])) +
           ((s[0] + s[1]) + (s[2] + s[3])) + s[4];
    w[1] = w[0] + s[5] - l[0];
    w[2] = w[1] + s[6] - l[1];
    w[3] = w[2] + s[7] - l[2];
    w[4] = w[3] + r[0] - l[3];
    w[5] = w[4] + r[1] - s[0];
    w[6] = w[5] + r[2] - s[1];
    w[7] = w[6] + r[3] - s[2];
}

// One wave = one 2-row band, full 512-col width; lane owns 8 output cols.
// Register-lean: rolled warm-up loop (no load hoisting), sequential hpass
// with shared transient, nw/od loaded AFTER the first hpass (L2 re-hit,
// TLP-hidden). Goal: VGPR <= 128 -> 4 waves/SIMD. launch_bounds(256,2) is
// a gentle cap only — (256,4) empirically forces 64 VGPR and spills.
__global__ __launch_bounds__(256, 2) void ncc_band_kernel(
    const float* __restrict__ I, const float* __restrict__ J,
    double* __restrict__ slots)
{
    const int lane = threadIdx.x & 63;
    const int wid  = threadIdx.x >> 6;
    const int band = blockIdx.x * 4 + wid;        // 0..4095
    const int img  = band >> 8;                   // 256 bands / image
    const int y0   = (band & 255) * BAND;
    const int col0 = lane * 8;

    const float* Ib = I + (size_t)img * IMG * IMG;
    const float* Jb = J + (size_t)img * IMG * IMG;

    float sI[8], sJ[8], sII[8], sJJ[8], sIJ[8];
    #pragma unroll
    for (int c = 0; c < 8; ++c) { sI[c]=0.f; sJ[c]=0.f; sII[c]=0.f; sJJ[c]=0.f; sIJ[c]=0.f; }

    // warm-up rows y0-4 .. y0+4 — deliberately rolled (caps live regs)
    for (int r = -4; r <= 4; ++r) {
        Rows rr = load_rows(Ib, Jb, y0 + r, col0);
        ACC_ROWS(rr)
    }

    float local = 0.0f;

    // sequential hpass: one shared transient, frees wI/wJ as soon as done
    auto hpass = [&]() {
        float wI[8], wJ[8], t[8], cross[8];
        hwin(sI, lane, wI);
        hwin(sJ, lane, wJ);
        hwin(sIJ, lane, t);
        #pragma unroll
        for (int k = 0; k < 8; ++k)
            cross[k] = fmaxf(fmaf(-wI[k] * INV81, wJ[k], t[k]), EPS);
        hwin(sII, lane, t);
        #pragma unroll
        for (int k = 0; k < 8; ++k)
            wI[k] = fmaxf(fmaf(-wI[k] * INV81, wI[k], t[k]), EPS);   // Iv
        hwin(sJJ, lane, t);
        #pragma unroll
        for (int k = 0; k < 8; ++k)
            wJ[k] = fmaxf(fmaf(-wJ[k] * INV81, wJ[k], t[k]), EPS);   // Jv
        #pragma unroll
        for (int k = 0; k < 8; ++k)
            local += (cross[k] * cross[k]) * __builtin_amdgcn_rcpf(wI[k] * wJ[k]);
    };

    hpass();                 // output row y0

    {   // slide: +row y0+5, -row y0-4 (y0-4 re-read -> L2 hit)
        Rows nw = load_rows(Ib, Jb, y0 + 5, col0);
        Rows od = load_rows(Ib, Jb, y0 - 4, col0);
        UPD_ROWS(nw, od)
    }

    hpass();                 // output row y0+1

    // wave reduction + private slot write (no atomic, no init needed)
    #pragma unroll
    for (int off = 32; off > 0; off >>= 1)
        local += __shfl_down(local, off, 64);
    if (lane == 0)
        slots[band] = (double)local;
}

__global__ __launch_bounds__(256) void ncc_finalize_kernel(
    const double* __restrict__ slots, float* __restrict__ out)
{
    const int tid = threadIdx.x;
    double t = 0.0;
    #pragma unroll
    for (int i = 0; i < NBANDS / 256; ++i)
        t += slots[tid + i * 256];
    #pragma unroll
    for (int off = 32; off > 0; off >>= 1)
        t += __shfl_down(t, off, 64);

    __shared__ double wsum[4];
    if ((tid & 63) == 0) wsum[tid >> 6] = t;
    __syncthreads();
    if (tid == 0)
        out[0] = (float)(-(wsum[0] + wsum[1] + wsum[2] + wsum[3]) / NPIX);
}

extern "C" void kernel_launch(void* const* d_in, const int* in_sizes, int n_in,
                              void* d_out, int out_size, void* d_ws, size_t ws_size,
                              hipStream_t stream)
{
    const float* I = (const float*)d_in[0];   // y_true
    const float* J = (const float*)d_in[1];   // y_pred
    float* out = (float*)d_out;
    double* slots = (double*)d_ws;            // 4096 doubles, all written each call

    // 4096 bands (16 images x 256 bands of 2 rows), 4 waves/block -> 1024 blocks
    ncc_band_kernel<<<1024, 256, 0, stream>>>(I, J, slots);
    ncc_finalize_kernel<<<1, 256, 0, stream>>>(slots, out);
}